// Round 7
// baseline (210.434 us; speedup 1.0000x reference)
//
#include <hip/hip_runtime.h>
#include <cstdint>

// ---------------- problem constants ----------------
static constexpr int B_  = 8192;
static constexpr int NW_ = 192;                 // NS + NV

typedef __attribute__((ext_vector_type(8))) _Float16 h8v;
typedef __attribute__((ext_vector_type(2))) _Float16 h2v;
typedef __attribute__((ext_vector_type(4))) float f4v;
typedef __attribute__((ext_vector_type(2))) float f2v;
typedef __attribute__((ext_vector_type(4))) unsigned u4v;

#define DI __device__ __forceinline__

DI h2v uh(unsigned u) { return __builtin_bit_cast(h2v, u); }
DI unsigned hu(h2v h) { return __builtin_bit_cast(unsigned, h); }
DI h2v hsplat(unsigned short bits) {
  _Float16 v = __builtin_bit_cast(_Float16, bits);
  h2v t; t.x = v; t.y = v; return t;
}
DI unsigned hpack(float lo, float hi) {
  h2v t; t.x = (_Float16)lo; t.y = (_Float16)hi;
  return __builtin_bit_cast(unsigned, t);
}
DI short f2h_bits(float f) { return __builtin_bit_cast(short, (_Float16)f); }

DI f4v mfma16h(h8v a, h8v b, f4v c) {
  return __builtin_amdgcn_mfma_f32_16x16x32_f16(a, b, c, 0, 0, 0);
}

// ---- block-symmetry tables (2 bits per block index) ----
static constexpr unsigned PK_BU0 = 606436u;   // {0,1,2,3,0,0,0,1,1,2}
static constexpr unsigned PK_BV0 = 1030628u;  // {0,1,2,3,1,2,3,2,3,3}
static constexpr unsigned PK_BU2 = 4u;        // {0,1,0}
static constexpr unsigned PK_BV2 = 20u;       // {0,1,1}
DI int tab2(unsigned pack, int blk) { return (int)((pack >> (2 * blk)) & 3u); }

// ---------------- prep: both weight tensors + accumulator zeroing, one launch ----------------
DI void prep_wsc_body(int g, const float* __restrict__ w000,
                      const float* __restrict__ w110, short* __restrict__ wf) {
  int lane = g & 63;
  int rest = g >> 6;
  int F = rest % 12;
  int s = rest / 12;
  int n = F * 16 + (lane & 15);
  int kk0 = (lane >> 4) << 3;
  const float s000 = 1.0f / (128.0f * 1.41421356237f);   // (1/N0) * inv_sqrt2
  const float s110 = 1.0f / (64.0f * 2.44948974968f);    // (1/(N1*sqrt3)) * inv_sqrt2
  short o[8];
  if (s < 320) {
    int blk = s >> 5, ik = s & 31;
    int bu = tab2(PK_BU0, blk), bv = tab2(PK_BV0, blk);
    int u = bu * 32 + ik;
#pragma unroll
    for (int j = 0; j < 8; ++j) {
      int v = bv * 32 + kk0 + j;
      float val = w000[(size_t)(u * 128 + v) * NW_ + n];
      if (bu != bv) val += w000[(size_t)(v * 128 + u) * NW_ + n];
      o[j] = f2h_bits(val * s000);
    }
  } else {
    int sp = s - 320;
    int blk = sp >> 5, ik = sp & 31;
    int bu = tab2(PK_BU2, blk), bv = tab2(PK_BV2, blk);
    int u = bu * 32 + ik;
#pragma unroll
    for (int j = 0; j < 8; ++j) {
      int v = bv * 32 + kk0 + j;
      float val = w110[(size_t)(u * 64 + v) * NW_ + n];
      if (bu != bv) val += w110[(size_t)(v * 64 + u) * NW_ + n];
      o[j] = f2h_bits(val * s110);
    }
  }
  *(h8v*)(wf + ((size_t)s * 12 + F) * 512 + lane * 8) = *(h8v*)o;
}

DI void prep_wvec_body(int g, const float* __restrict__ w011,
                       const float* __restrict__ w111, short* __restrict__ wf) {
  int lane = g & 63;
  int nf = (g >> 6) & 3;
  int s = g >> 8;
  int n = nf * 16 + (lane & 15);
  int kk0 = (lane >> 4) << 3;
  const float sv = 1.0f / 128.0f;
  short o[8];
  if (s < 256) {
#pragma unroll
    for (int j = 0; j < 8; ++j) {
      int k = s * 32 + kk0 + j;
      o[j] = f2h_bits(w011[(size_t)k * 64 + n] * sv);
    }
  } else {
    int sp = s - 256;
    int blk = sp >> 5, ik = sp & 31;
    int bu = tab2(PK_BU2, blk), bv = tab2(PK_BV2, blk);
    int u = bu * 32 + ik;
#pragma unroll
    for (int j = 0; j < 8; ++j) {
      int v = bv * 32 + kk0 + j;
      float val = w111[(size_t)(u * 64 + v) * 64 + n];
      if (bu != bv) val -= w111[(size_t)(v * 64 + u) * 64 + n];
      o[j] = f2h_bits(val * sv);
    }
  }
  *(h8v*)(wf + ((size_t)s * 4 + nf) * 512 + lane * 8) = *(h8v*)o;
}

// blocks [0,1248): wsc prep; [1248,1600): wvec prep; [1600,4672): zero 12.58 MB of acc
__global__ void prep_all(const float* __restrict__ w000, const float* __restrict__ w110,
                         const float* __restrict__ w011, const float* __restrict__ w111,
                         short* __restrict__ wsc, short* __restrict__ wve,
                         float* __restrict__ acc) {
  if (blockIdx.x < 1248) {
    prep_wsc_body(blockIdx.x * 256 + threadIdx.x, w000, w110, wsc);
  } else if (blockIdx.x < 1600) {
    prep_wvec_body((blockIdx.x - 1248) * 256 + threadIdx.x, w011, w111, wve);
  } else {
    int idx = (blockIdx.x - 1600) * 256 + threadIdx.x;  // 786432 threads x 16 B
    *(f4v*)(acc + (size_t)idx * 4) = f4v{0.f, 0.f, 0.f, 0.f};
  }
}

// ---------------- shared LDS staging: 64 rows of x, f16, 256 threads (2 passes) ----------------
#define X0H_STRIDE 136
#define X1_STRIDE  200

DI void stage_x64(const float* __restrict__ x, int b0,
                  unsigned short* X0H, unsigned short* X1) {
  const int t = threadIdx.x;            // 256 threads
#pragma unroll
  for (int pass = 0; pass < 2; ++pass) {
    const int row = pass * 32 + (t >> 3), l8 = t & 7;
    const float* src = x + (size_t)(b0 + row) * 320;
    unsigned o[8];
#pragma unroll
    for (int j = 0; j < 4; ++j) {
      f4v v = *(const f4v*)(src + l8 * 16 + j * 4);
      o[2 * j]     = hpack(v.x, v.y);
      o[2 * j + 1] = hpack(v.z, v.w);
    }
    *(u4v*)(&X0H[row * X0H_STRIDE + l8 * 16])     = u4v{o[0], o[1], o[2], o[3]};
    *(u4v*)(&X0H[row * X0H_STRIDE + l8 * 16 + 8]) = u4v{o[4], o[5], o[6], o[7]};
    float buf[24];
#pragma unroll
    for (int j = 0; j < 12; ++j) {
      f2v v = *(const f2v*)(src + 128 + l8 * 24 + j * 2);
      buf[2 * j] = v.x; buf[2 * j + 1] = v.y;
    }
#pragma unroll
    for (int i = 0; i < 3; ++i) {
      u4v w;
#pragma unroll
      for (int e = 0; e < 4; ++e)
        w[e] = hpack(buf[(2 * e) * 3 + i], buf[(2 * e + 1) * 3 + i]);
      *(u4v*)(&X1[row * X1_STRIDE + i * 64 + l8 * 8]) = w;
    }
  }
}

DI void loadB6(h8v* dst, const short* __restrict__ p) {
#pragma unroll
  for (int nf = 0; nf < 6; ++nf) dst[nf] = *(const h8v*)(p + nf * 512);
}
DI void loadB4(h8v* dst, const short* __restrict__ p) {
#pragma unroll
  for (int nf = 0; nf < 4; ++nf) dst[nf] = *(const h8v*)(p + nf * 512);
}

// ---------------- fused GEMM: XCD-affine (path,kb) mapping ----------------
// R7: combo = blockIdx.x & 7 == XCD id (round-robin dispatch). path = combo&1,
// kb = combo>>1. Each XCD reads ONLY its own chunk-pair of weights:
// sc-XCDs ~1.28 MB, vec-XCDs ~0.36 MB — resident in the 4 MB per-XCD L2, so
// every block's B-loads are L2 hits instead of L3/HBM misses (R6 measured:
// FETCH 45 MB >> 17 MB inputs = full-working-set thrash on every XCD).
// Keeps R6's 4-frag/wave AI (24 MFMA per B-load set).
__global__ __launch_bounds__(256, 2)
void gemm_fused(const float* __restrict__ x, const short* __restrict__ wsc,
                const short* __restrict__ wve,
                float* __restrict__ acc_sc, float* __restrict__ acc_ve) {
  __shared__ unsigned short X0H[64 * X0H_STRIDE];
  __shared__ unsigned short X1[64 * X1_STRIDE];
  const int combo = blockIdx.x & 7;     // XCD id under round-robin dispatch
  const int path = combo & 1;
  const int kb = combo >> 1;
  const int b0 = (blockIdx.x >> 3) * 64;

  stage_x64(x, b0, X0H, X1);
  __syncthreads();

  const int t0 = threadIdx.x;
  const int w = t0 >> 6, lane = t0 & 63;   // w in 0..3
  const int q = lane >> 4, r = lane & 15, q8 = q * 8;

  if (path == 0) {
    // ================= scalar path =================
    const int nh = w & 1, kh = w >> 1;
    const int c = kb * 2 + kh;          // chunk 0..7
    const unsigned short* x0f[4];
    const unsigned short* x1f[4];
#pragma unroll
    for (int f = 0; f < 4; ++f) {
      x0f[f] = &X0H[(f * 16 + r) * X0H_STRIDE];
      x1f[f] = &X1[(f * 16 + r) * X1_STRIDE];
    }

    f4v acc[4][6];
#pragma unroll
    for (int f = 0; f < 4; ++f)
#pragma unroll
      for (int nf = 0; nf < 6; ++nf) acc[f][nf] = f4v{0.f, 0.f, 0.f, 0.f};

    // ---- region 1: x0 pair blocks, 40 steps ----
    {
      const short* wp = wsc + ((size_t)(c * 40) * 12 + nh * 6) * 512 + lane * 8;
      u4v pv[4];
#pragma unroll
      for (int f = 0; f < 4; ++f) pv[f] = u4v{0, 0, 0, 0};
      int bu32 = 0;
      h8v ba[6], bb[6];
      loadB6(ba, wp);
      auto step = [&](int t, const h8v* b) {
        const int s = c * 40 + t;
        const int ik = s & 31;
        if (t == 0 || ik == 0) {        // new 32x32 block: reload v-strips (wave-uniform)
          const int blk = s >> 5;
          const int bv32 = tab2(PK_BV0, blk) * 32;
          bu32 = tab2(PK_BU0, blk) * 32;
#pragma unroll
          for (int f = 0; f < 4; ++f) pv[f] = *(const u4v*)(x0f[f] + bv32 + q8);
        }
        h8v a[4];
#pragma unroll
        for (int f = 0; f < 4; ++f) {
          h2v xu = hsplat(x0f[f][bu32 + ik]);
          u4v pa;
#pragma unroll
          for (int m = 0; m < 4; ++m) pa[m] = hu(uh(pv[f][m]) * xu);
          a[f] = __builtin_bit_cast(h8v, pa);
        }
        __builtin_amdgcn_s_setprio(1);
#pragma unroll
        for (int nf = 0; nf < 6; ++nf)
#pragma unroll
          for (int f = 0; f < 4; ++f)
            acc[f][nf] = mfma16h(a[f], b[nf], acc[f][nf]);
        __builtin_amdgcn_s_setprio(0);
      };
      for (int t2 = 0; t2 < 20; ++t2) {
        loadB6(bb, wp + 6144);          // prefetch odd step
        step(2 * t2, ba);
        if (t2 != 19) loadB6(ba, wp + 12288);  // prefetch next even step
        step(2 * t2 + 1, bb);
        wp += 12288;
      }
    }

    // ---- region 2: x1-dots pair blocks, 12 steps ----
    {
      const short* wp = wsc + ((size_t)(320 + c * 12) * 12 + nh * 6) * 512 + lane * 8;
      h8v ba[6], bb[6];
      loadB6(ba, wp);
      auto step = [&](int t, const h8v* b) {
        const int sp = c * 12 + t;
        const int blk = sp >> 5, ik = sp & 31;
        const int bu32 = tab2(PK_BU2, blk) * 32;
        const int bv32 = tab2(PK_BV2, blk) * 32;
        h8v a[4];
#pragma unroll
        for (int f = 0; f < 4; ++f) {
          h2v us0 = hsplat(x1f[f][bu32 + ik]);
          h2v us1 = hsplat(x1f[f][64 + bu32 + ik]);
          h2v us2 = hsplat(x1f[f][128 + bu32 + ik]);
          u4v p0 = *(const u4v*)(x1f[f] + bv32 + q8);
          u4v p1 = *(const u4v*)(x1f[f] + 64 + bv32 + q8);
          u4v p2 = *(const u4v*)(x1f[f] + 128 + bv32 + q8);
          u4v pa;
#pragma unroll
          for (int m = 0; m < 4; ++m) {
            h2v sm = uh(p0[m]) * us0;
            sm = sm + uh(p1[m]) * us1;
            sm = sm + uh(p2[m]) * us2;
            pa[m] = hu(sm);
          }
          a[f] = __builtin_bit_cast(h8v, pa);
        }
        __builtin_amdgcn_s_setprio(1);
#pragma unroll
        for (int nf = 0; nf < 6; ++nf)
#pragma unroll
          for (int f = 0; f < 4; ++f)
            acc[f][nf] = mfma16h(a[f], b[nf], acc[f][nf]);
        __builtin_amdgcn_s_setprio(0);
      };
      for (int t2 = 0; t2 < 6; ++t2) {
        loadB6(bb, wp + 6144);
        step(2 * t2, ba);
        if (t2 != 5) loadB6(ba, wp + 12288);
        step(2 * t2 + 1, bb);
        wp += 12288;
      }
    }

#pragma unroll
    for (int f = 0; f < 4; ++f)
#pragma unroll
      for (int nf = 0; nf < 6; ++nf) {
        int n = (nh * 6 + nf) * 16 + r;
#pragma unroll
        for (int reg = 0; reg < 4; ++reg) {
          int rowo = b0 + f * 16 + q * 4 + reg;
          atomicAdd(&acc_sc[(size_t)rowo * NW_ + n], acc[f][nf][reg]);
        }
      }
  } else {
    // ================= vector path =================
    const int fg = w & 1, kh = w >> 1;
    const int c = kb * 2 + kh;          // chunk 0..7
    const unsigned short* x0r[2];
    const unsigned short* x1r[2];
#pragma unroll
    for (int ff = 0; ff < 2; ++ff) {
      int row = fg * 32 + ff * 16 + r;
      x0r[ff] = &X0H[row * X0H_STRIDE];
      x1r[ff] = &X1[row * X1_STRIDE];
    }

    f4v acc[2][3][4];
#pragma unroll
    for (int ff = 0; ff < 2; ++ff)
#pragma unroll
      for (int ip = 0; ip < 3; ++ip)
#pragma unroll
        for (int nf = 0; nf < 4; ++nf) acc[ff][ip][nf] = f4v{0.f, 0.f, 0.f, 0.f};

    // ---- region 1: v011 (x0 * x1[ip]), 32 steps (flattened g x j) ----
    {
      const int u0 = c * 16;
      const short* wp = wve + (size_t)(c * 32) * 2048 + lane * 8;
      h8v ba[4], bb[4];
      loadB4(ba, wp);
      auto vstep = [&](int st, const h8v* b) {
        const int g = st >> 1, j = st & 1;
        const int vb = j * 32 + q8;
        h8v a[2][3];
#pragma unroll
        for (int ff = 0; ff < 2; ++ff) {
          h2v xu2 = hsplat(x0r[ff][u0 + g]);
#pragma unroll
          for (int i = 0; i < 3; ++i) {
            u4v p = *(const u4v*)(x1r[ff] + i * 64 + vb);
            u4v pa;
#pragma unroll
            for (int m = 0; m < 4; ++m) pa[m] = hu(uh(p[m]) * xu2);
            a[ff][i] = __builtin_bit_cast(h8v, pa);
          }
        }
        __builtin_amdgcn_s_setprio(1);
#pragma unroll
        for (int ip = 0; ip < 3; ++ip)
#pragma unroll
          for (int nf = 0; nf < 4; ++nf)
#pragma unroll
            for (int ff = 0; ff < 2; ++ff)
              acc[ff][ip][nf] = mfma16h(a[ff][ip], b[nf], acc[ff][ip][nf]);
        __builtin_amdgcn_s_setprio(0);
      };
      for (int t2 = 0; t2 < 16; ++t2) {
        loadB4(bb, wp + 2048);
        vstep(2 * t2, ba);
        if (t2 != 15) loadB4(ba, wp + 4096);
        vstep(2 * t2 + 1, bb);
        wp += 4096;
      }
    }

    // ---- region 2: v111 antisym pair blocks, 12 steps ----
    {
      const short* wp = wve + (size_t)(256 + c * 12) * 2048 + lane * 8;
      h8v ba[4], bb[4];
      loadB4(ba, wp);
      auto vstep = [&](int t, const h8v* b) {
        const int sp = c * 12 + t;
        const int blk = sp >> 5, ik = sp & 31;
        const int bu32 = tab2(PK_BU2, blk) * 32;
        const int bv32 = tab2(PK_BV2, blk) * 32;
        h8v a[2][3];
#pragma unroll
        for (int ff = 0; ff < 2; ++ff) {
          h2v us[3];
          u4v p[3];
#pragma unroll
          for (int i = 0; i < 3; ++i) {
            us[i] = hsplat(x1r[ff][i * 64 + bu32 + ik]);
            p[i] = *(const u4v*)(x1r[ff] + i * 64 + bv32 + q8);
          }
#pragma unroll
          for (int ip = 0; ip < 3; ++ip) {
            const int i1 = (ip + 1) % 3, i2 = (ip + 2) % 3;
            u4v pa;
#pragma unroll
            for (int m = 0; m < 4; ++m)
              pa[m] = hu(uh(p[i2][m]) * us[i1] - uh(p[i1][m]) * us[i2]);
            a[ff][ip] = __builtin_bit_cast(h8v, pa);
          }
        }
        __builtin_amdgcn_s_setprio(1);
#pragma unroll
        for (int ip = 0; ip < 3; ++ip)
#pragma unroll
          for (int nf = 0; nf < 4; ++nf)
#pragma unroll
            for (int ff = 0; ff < 2; ++ff)
              acc[ff][ip][nf] = mfma16h(a[ff][ip], b[nf], acc[ff][ip][nf]);
        __builtin_amdgcn_s_setprio(0);
      };
      for (int t2 = 0; t2 < 6; ++t2) {
        loadB4(bb, wp + 2048);
        vstep(2 * t2, ba);
        if (t2 != 5) loadB4(ba, wp + 4096);
        vstep(2 * t2 + 1, bb);
        wp += 4096;
      }
    }

#pragma unroll
    for (int ff = 0; ff < 2; ++ff)
#pragma unroll
      for (int ip = 0; ip < 3; ++ip)
#pragma unroll
        for (int nf = 0; nf < 4; ++nf) {
          int n = nf * 16 + r;
#pragma unroll
          for (int reg = 0; reg < 4; ++reg) {
            int rowo = ip * B_ + b0 + fg * 32 + ff * 16 + q * 4 + reg;
            atomicAdd(&acc_ve[(size_t)rowo * 64 + n], acc[ff][ip][nf][reg]);
          }
        }
  }
}

// ---------------- epilogue: silu / sigmoid-gating, interleaved output ----------------
__global__ void epilogue(const float* __restrict__ sc, const float* __restrict__ ve,
                         float* __restrict__ out) {
  int t = blockIdx.x * blockDim.x + threadIdx.x;  // B*192 threads exactly
  int b = t / NW_, c = t % NW_;
  float v = sc[t];
  float sg = 1.0f / (1.0f + __expf(-v));
  if (c < 128) {
    out[(size_t)b * 320 + c] = v * sg;            // silu
  } else {
    int w = c - 128;
#pragma unroll
    for (int i = 0; i < 3; ++i) {
      float vv = ve[((size_t)i * B_ + b) * 64 + w];
      out[(size_t)b * 320 + 128 + w * 3 + i] = vv * sg;
    }
  }
}

// ---------------- launch ----------------
extern "C" void kernel_launch(void* const* d_in, const int* in_sizes, int n_in,
                              void* d_out, int out_size, void* d_ws, size_t ws_size,
                              hipStream_t stream) {
  const float* x    = (const float*)d_in[0];
  const float* w000 = (const float*)d_in[1];
  const float* w110 = (const float*)d_in[2];
  const float* w011 = (const float*)d_in[3];
  const float* w111 = (const float*)d_in[4];
  float* out = (float*)d_out;

  char* ws = (char*)d_ws;
  float* acc_sc = (float*)ws;                     // 8192*192*4  = 6,291,456 B
  float* acc_ve = (float*)(ws + 6291456);         // 3*8192*64*4 = 6,291,456 B
  short* wsc    = (short*)(ws + 12582912);        // 416*12*512*2 = 5,111,808 B
  short* wve    = (short*)(ws + 17694720);        // 352*4*512*2  = 1,441,792 B
  // total ws use: 19,136,512 B

  // prep_all also zeroes both accumulators (blocks 1600..4671) — no hipMemsetAsync
  prep_all  <<<4672, 256, 0, stream>>>(w000, w110, w011, w111, wsc, wve, acc_sc);
  gemm_fused<<<1024, 256, 0, stream>>>(x, wsc, wve, acc_sc, acc_ve);
  epilogue  <<<6144, 256, 0, stream>>>(acc_sc, acc_ve, out);
}

// Round 8
// 178.784 us; speedup vs baseline: 1.1770x; 1.1770x over previous
//
#include <hip/hip_runtime.h>
#include <cstdint>

// ---------------- problem constants ----------------
static constexpr int B_  = 8192;
static constexpr int NW_ = 192;                 // NS + NV

typedef __attribute__((ext_vector_type(8))) _Float16 h8v;
typedef __attribute__((ext_vector_type(2))) _Float16 h2v;
typedef __attribute__((ext_vector_type(4))) float f4v;
typedef __attribute__((ext_vector_type(2))) float f2v;
typedef __attribute__((ext_vector_type(4))) unsigned u4v;

#define DI __device__ __forceinline__

DI h2v uh(unsigned u) { return __builtin_bit_cast(h2v, u); }
DI unsigned hu(h2v h) { return __builtin_bit_cast(unsigned, h); }
DI h2v hsplat(unsigned short bits) {
  _Float16 v = __builtin_bit_cast(_Float16, bits);
  h2v t; t.x = v; t.y = v; return t;
}
DI unsigned hpack(float lo, float hi) {
  h2v t; t.x = (_Float16)lo; t.y = (_Float16)hi;
  return __builtin_bit_cast(unsigned, t);
}
DI short f2h_bits(float f) { return __builtin_bit_cast(short, (_Float16)f); }

DI f4v mfma16h(h8v a, h8v b, f4v c) {
  return __builtin_amdgcn_mfma_f32_16x16x32_f16(a, b, c, 0, 0, 0);
}

// ---- block-symmetry tables (2 bits per block index) ----
static constexpr unsigned PK_BU0 = 606436u;   // {0,1,2,3,0,0,0,1,1,2}
static constexpr unsigned PK_BV0 = 1030628u;  // {0,1,2,3,1,2,3,2,3,3}
static constexpr unsigned PK_BU2 = 4u;        // {0,1,0}
static constexpr unsigned PK_BV2 = 20u;       // {0,1,1}
DI int tab2(unsigned pack, int blk) { return (int)((pack >> (2 * blk)) & 3u); }

// ---------------- prep: both weight tensors, one launch ----------------
DI void prep_wsc_body(int g, const float* __restrict__ w000,
                      const float* __restrict__ w110, short* __restrict__ wf) {
  int lane = g & 63;
  int rest = g >> 6;
  int F = rest % 12;
  int s = rest / 12;
  int n = F * 16 + (lane & 15);
  int kk0 = (lane >> 4) << 3;
  const float s000 = 1.0f / (128.0f * 1.41421356237f);   // (1/N0) * inv_sqrt2
  const float s110 = 1.0f / (64.0f * 2.44948974968f);    // (1/(N1*sqrt3)) * inv_sqrt2
  short o[8];
  if (s < 320) {
    int blk = s >> 5, ik = s & 31;
    int bu = tab2(PK_BU0, blk), bv = tab2(PK_BV0, blk);
    int u = bu * 32 + ik;
#pragma unroll
    for (int j = 0; j < 8; ++j) {
      int v = bv * 32 + kk0 + j;
      float val = w000[(size_t)(u * 128 + v) * NW_ + n];
      if (bu != bv) val += w000[(size_t)(v * 128 + u) * NW_ + n];
      o[j] = f2h_bits(val * s000);
    }
  } else {
    int sp = s - 320;
    int blk = sp >> 5, ik = sp & 31;
    int bu = tab2(PK_BU2, blk), bv = tab2(PK_BV2, blk);
    int u = bu * 32 + ik;
#pragma unroll
    for (int j = 0; j < 8; ++j) {
      int v = bv * 32 + kk0 + j;
      float val = w110[(size_t)(u * 64 + v) * NW_ + n];
      if (bu != bv) val += w110[(size_t)(v * 64 + u) * NW_ + n];
      o[j] = f2h_bits(val * s110);
    }
  }
  *(h8v*)(wf + ((size_t)s * 12 + F) * 512 + lane * 8) = *(h8v*)o;
}

DI void prep_wvec_body(int g, const float* __restrict__ w011,
                       const float* __restrict__ w111, short* __restrict__ wf) {
  int lane = g & 63;
  int nf = (g >> 6) & 3;
  int s = g >> 8;
  int n = nf * 16 + (lane & 15);
  int kk0 = (lane >> 4) << 3;
  const float sv = 1.0f / 128.0f;
  short o[8];
  if (s < 256) {
#pragma unroll
    for (int j = 0; j < 8; ++j) {
      int k = s * 32 + kk0 + j;
      o[j] = f2h_bits(w011[(size_t)k * 64 + n] * sv);
    }
  } else {
    int sp = s - 256;
    int blk = sp >> 5, ik = sp & 31;
    int bu = tab2(PK_BU2, blk), bv = tab2(PK_BV2, blk);
    int u = bu * 32 + ik;
#pragma unroll
    for (int j = 0; j < 8; ++j) {
      int v = bv * 32 + kk0 + j;
      float val = w111[(size_t)(u * 64 + v) * 64 + n];
      if (bu != bv) val -= w111[(size_t)(v * 64 + u) * 64 + n];
      o[j] = f2h_bits(val * sv);
    }
  }
  *(h8v*)(wf + ((size_t)s * 4 + nf) * 512 + lane * 8) = *(h8v*)o;
}

// blocks [0,1248): wsc prep; [1248,1600): wvec prep. No accumulator zeroing —
// R8's gemm writes every acc element exactly once (plain stores, no atomics).
__global__ void prep_all(const float* __restrict__ w000, const float* __restrict__ w110,
                         const float* __restrict__ w011, const float* __restrict__ w111,
                         short* __restrict__ wsc, short* __restrict__ wve) {
  if (blockIdx.x < 1248) {
    prep_wsc_body(blockIdx.x * 256 + threadIdx.x, w000, w110, wsc);
  } else {
    prep_wvec_body((blockIdx.x - 1248) * 256 + threadIdx.x, w011, w111, wve);
  }
}

// ---------------- shared LDS staging: 32 rows of x, f16 ----------------
#define X0H_STRIDE 136
#define X1_STRIDE  200

DI void stage_x32(const float* __restrict__ x, int b0,
                  unsigned short* X0H, unsigned short* X1) {
  const int t = threadIdx.x;            // 256 threads
  const int row = t >> 3, l8 = t & 7;   // 32 rows x 8 lanes
  const float* src = x + (size_t)(b0 + row) * 320;
  unsigned o[8];
#pragma unroll
  for (int j = 0; j < 4; ++j) {
    f4v v = *(const f4v*)(src + l8 * 16 + j * 4);
    o[2 * j]     = hpack(v.x, v.y);
    o[2 * j + 1] = hpack(v.z, v.w);
  }
  *(u4v*)(&X0H[row * X0H_STRIDE + l8 * 16])     = u4v{o[0], o[1], o[2], o[3]};
  *(u4v*)(&X0H[row * X0H_STRIDE + l8 * 16 + 8]) = u4v{o[4], o[5], o[6], o[7]};
  float buf[24];
#pragma unroll
  for (int j = 0; j < 12; ++j) {
    f2v v = *(const f2v*)(src + 128 + l8 * 24 + j * 2);
    buf[2 * j] = v.x; buf[2 * j + 1] = v.y;
  }
#pragma unroll
  for (int i = 0; i < 3; ++i) {
    u4v w;
#pragma unroll
    for (int e = 0; e < 4; ++e)
      w[e] = hpack(buf[(2 * e) * 3 + i], buf[(2 * e + 1) * 3 + i]);
    *(u4v*)(&X1[row * X1_STRIDE + i * 64 + l8 * 8]) = w;
  }
}

DI void loadB6(h8v* dst, const short* __restrict__ p) {
#pragma unroll
  for (int nf = 0; nf < 6; ++nf) dst[nf] = *(const h8v*)(p + nf * 512);
}
DI void loadB2(h8v* dst, const short* __restrict__ p) {
  dst[0] = *(const h8v*)p;
  dst[1] = *(const h8v*)(p + 512);
}

// ---------------- fused GEMM, NO global atomics ----------------
// R8: each output element is produced by exactly ONE block. 32-row tiles,
// grid 512 = 8 xcd x 64 (path alternates within XCD for balance). Waves =
// nh(2: n-halves) x kh(2: K-halves); the kh pair is merged via a 24 KB LDS
// dump + add, then PLAIN stores. This removes the 25.2M global atomicAdds
// that R1-R7 shared (WRITE_SIZE 100 MB vs 12.6 MB acc = 8x amplification;
// atomic-throughput wall explains the invariant ~130 us across all configs).
__global__ __launch_bounds__(256, 2)
void gemm_fused(const float* __restrict__ x, const short* __restrict__ wsc,
                const short* __restrict__ wve,
                float* __restrict__ acc_sc, float* __restrict__ acc_ve) {
  __shared__ unsigned short X0H[32 * X0H_STRIDE];
  __shared__ unsigned short X1[32 * X1_STRIDE];
  __shared__ f4v dump[2][12][64];       // [nh][acc-slot][lane]
  const int xcd = blockIdx.x & 7;
  const int wi  = blockIdx.x >> 3;      // 0..63 within-XCD under round-robin
  const int path = wi & 1;
  const int tile = xcd * 32 + (wi >> 1);  // 0..255, bijective
  const int b0 = tile * 32;

  stage_x32(x, b0, X0H, X1);
  __syncthreads();

  const int t0 = threadIdx.x;
  const int w = t0 >> 6, lane = t0 & 63;   // w in 0..3
  const int nh = w & 1, kh = w >> 1;
  const int q = lane >> 4, r = lane & 15, q8 = q * 8;

  if (path == 0) {
    // ================= scalar path =================
    const unsigned short* x0f[2];
    const unsigned short* x1f[2];
#pragma unroll
    for (int f = 0; f < 2; ++f) {
      x0f[f] = &X0H[(f * 16 + r) * X0H_STRIDE];
      x1f[f] = &X1[(f * 16 + r) * X1_STRIDE];
    }

    f4v acc[2][6];
#pragma unroll
    for (int f = 0; f < 2; ++f)
#pragma unroll
      for (int nf = 0; nf < 6; ++nf) acc[f][nf] = f4v{0.f, 0.f, 0.f, 0.f};

    // ---- region 1: x0 pair blocks, 160 steps (K-half kh) ----
    {
      const int s0 = kh * 160;
      const short* wp = wsc + ((size_t)s0 * 12 + nh * 6) * 512 + lane * 8;
      u4v pv[2];
#pragma unroll
      for (int f = 0; f < 2; ++f) pv[f] = u4v{0, 0, 0, 0};
      int bu32 = 0;
      h8v ba[6], bb[6];
      loadB6(ba, wp);
      auto step = [&](int t, const h8v* b) {
        const int s = s0 + t;
        const int ik = s & 31;
        if (t == 0 || ik == 0) {        // new 32x32 block: reload v-strips (wave-uniform)
          const int blk = s >> 5;
          const int bv32 = tab2(PK_BV0, blk) * 32;
          bu32 = tab2(PK_BU0, blk) * 32;
#pragma unroll
          for (int f = 0; f < 2; ++f) pv[f] = *(const u4v*)(x0f[f] + bv32 + q8);
        }
        h8v a[2];
#pragma unroll
        for (int f = 0; f < 2; ++f) {
          h2v xu = hsplat(x0f[f][bu32 + ik]);
          u4v pa;
#pragma unroll
          for (int m = 0; m < 4; ++m) pa[m] = hu(uh(pv[f][m]) * xu);
          a[f] = __builtin_bit_cast(h8v, pa);
        }
        __builtin_amdgcn_s_setprio(1);
#pragma unroll
        for (int nf = 0; nf < 6; ++nf)
#pragma unroll
          for (int f = 0; f < 2; ++f)
            acc[f][nf] = mfma16h(a[f], b[nf], acc[f][nf]);
        __builtin_amdgcn_s_setprio(0);
      };
      for (int t2 = 0; t2 < 80; ++t2) {
        loadB6(bb, wp + 6144);          // prefetch odd step
        step(2 * t2, ba);
        if (t2 != 79) loadB6(ba, wp + 12288);  // prefetch next even step
        step(2 * t2 + 1, bb);
        wp += 12288;
      }
    }

    // ---- region 2: x1-dots pair blocks, 48 steps (K-half kh) ----
    {
      const int sp0 = kh * 48;
      const short* wp = wsc + ((size_t)(320 + sp0) * 12 + nh * 6) * 512 + lane * 8;
      h8v ba[6], bb[6];
      loadB6(ba, wp);
      auto step = [&](int t, const h8v* b) {
        const int sp = sp0 + t;
        const int blk = sp >> 5, ik = sp & 31;
        const int bu32 = tab2(PK_BU2, blk) * 32;
        const int bv32 = tab2(PK_BV2, blk) * 32;
        h8v a[2];
#pragma unroll
        for (int f = 0; f < 2; ++f) {
          h2v us0 = hsplat(x1f[f][bu32 + ik]);
          h2v us1 = hsplat(x1f[f][64 + bu32 + ik]);
          h2v us2 = hsplat(x1f[f][128 + bu32 + ik]);
          u4v p0 = *(const u4v*)(x1f[f] + bv32 + q8);
          u4v p1 = *(const u4v*)(x1f[f] + 64 + bv32 + q8);
          u4v p2 = *(const u4v*)(x1f[f] + 128 + bv32 + q8);
          u4v pa;
#pragma unroll
          for (int m = 0; m < 4; ++m) {
            h2v sm = uh(p0[m]) * us0;
            sm = sm + uh(p1[m]) * us1;
            sm = sm + uh(p2[m]) * us2;
            pa[m] = hu(sm);
          }
          a[f] = __builtin_bit_cast(h8v, pa);
        }
        __builtin_amdgcn_s_setprio(1);
#pragma unroll
        for (int nf = 0; nf < 6; ++nf)
#pragma unroll
          for (int f = 0; f < 2; ++f)
            acc[f][nf] = mfma16h(a[f], b[nf], acc[f][nf]);
        __builtin_amdgcn_s_setprio(0);
      };
      for (int t2 = 0; t2 < 24; ++t2) {
        loadB6(bb, wp + 6144);
        step(2 * t2, ba);
        if (t2 != 23) loadB6(ba, wp + 12288);
        step(2 * t2 + 1, bb);
        wp += 12288;
      }
    }

    // ---- kh-pair reduce in LDS, then plain store ----
    if (kh == 1) {
#pragma unroll
      for (int f = 0; f < 2; ++f)
#pragma unroll
        for (int nf = 0; nf < 6; ++nf)
          dump[nh][f * 6 + nf][lane] = acc[f][nf];
    }
    __syncthreads();
    if (kh == 0) {
#pragma unroll
      for (int f = 0; f < 2; ++f)
#pragma unroll
        for (int nf = 0; nf < 6; ++nf) {
          f4v v = acc[f][nf] + dump[nh][f * 6 + nf][lane];
          int n = (nh * 6 + nf) * 16 + r;
#pragma unroll
          for (int reg = 0; reg < 4; ++reg) {
            int rowo = b0 + f * 16 + q * 4 + reg;
            acc_sc[(size_t)rowo * NW_ + n] = v[reg];
          }
        }
    }
  } else {
    // ================= vector path =================
    const unsigned short* x0r[2];
    const unsigned short* x1r[2];
#pragma unroll
    for (int ff = 0; ff < 2; ++ff) {
      x0r[ff] = &X0H[(ff * 16 + r) * X0H_STRIDE];
      x1r[ff] = &X1[(ff * 16 + r) * X1_STRIDE];
    }

    f4v acc[2][3][2];                   // [ff][ip][nfl]
#pragma unroll
    for (int ff = 0; ff < 2; ++ff)
#pragma unroll
      for (int ip = 0; ip < 3; ++ip)
#pragma unroll
        for (int nfl = 0; nfl < 2; ++nfl) acc[ff][ip][nfl] = f4v{0.f, 0.f, 0.f, 0.f};

    // ---- region 1: v011, 128 steps (u in [kh*64, +64), j in {0,1}) ----
    {
      const int u0 = kh * 64;
      const short* wp = wve + (size_t)(u0 * 2) * 2048 + nh * 1024 + lane * 8;
      h8v ba[2], bb[2];
      loadB2(ba, wp);
      auto vstep = [&](int st, const h8v* b) {
        const int g = st >> 1, j = st & 1;
        const int vb = j * 32 + q8;
        h8v a[2][3];
#pragma unroll
        for (int ff = 0; ff < 2; ++ff) {
          h2v xu2 = hsplat(x0r[ff][u0 + g]);
#pragma unroll
          for (int i = 0; i < 3; ++i) {
            u4v p = *(const u4v*)(x1r[ff] + i * 64 + vb);
            u4v pa;
#pragma unroll
            for (int m = 0; m < 4; ++m) pa[m] = hu(uh(p[m]) * xu2);
            a[ff][i] = __builtin_bit_cast(h8v, pa);
          }
        }
        __builtin_amdgcn_s_setprio(1);
#pragma unroll
        for (int ip = 0; ip < 3; ++ip)
#pragma unroll
          for (int nfl = 0; nfl < 2; ++nfl)
#pragma unroll
            for (int ff = 0; ff < 2; ++ff)
              acc[ff][ip][nfl] = mfma16h(a[ff][ip], b[nfl], acc[ff][ip][nfl]);
        __builtin_amdgcn_s_setprio(0);
      };
      for (int t2 = 0; t2 < 64; ++t2) {
        loadB2(bb, wp + 2048);
        vstep(2 * t2, ba);
        if (t2 != 63) loadB2(ba, wp + 4096);
        vstep(2 * t2 + 1, bb);
        wp += 4096;
      }
    }

    // ---- region 2: v111 antisym, 48 steps (sp in [kh*48, +48)) ----
    {
      const int sp0 = kh * 48;
      const short* wp = wve + (size_t)(256 + sp0) * 2048 + nh * 1024 + lane * 8;
      h8v ba[2], bb[2];
      loadB2(ba, wp);
      auto vstep = [&](int t, const h8v* b) {
        const int sp = sp0 + t;
        const int blk = sp >> 5, ik = sp & 31;
        const int bu32 = tab2(PK_BU2, blk) * 32;
        const int bv32 = tab2(PK_BV2, blk) * 32;
        h8v a[2][3];
#pragma unroll
        for (int ff = 0; ff < 2; ++ff) {
          h2v us[3];
          u4v p[3];
#pragma unroll
          for (int i = 0; i < 3; ++i) {
            us[i] = hsplat(x1r[ff][i * 64 + bu32 + ik]);
            p[i] = *(const u4v*)(x1r[ff] + i * 64 + bv32 + q8);
          }
#pragma unroll
          for (int ip = 0; ip < 3; ++ip) {
            const int i1 = (ip + 1) % 3, i2 = (ip + 2) % 3;
            u4v pa;
#pragma unroll
            for (int m = 0; m < 4; ++m)
              pa[m] = hu(uh(p[i2][m]) * us[i1] - uh(p[i1][m]) * us[i2]);
            a[ff][ip] = __builtin_bit_cast(h8v, pa);
          }
        }
        __builtin_amdgcn_s_setprio(1);
#pragma unroll
        for (int ip = 0; ip < 3; ++ip)
#pragma unroll
          for (int nfl = 0; nfl < 2; ++nfl)
#pragma unroll
            for (int ff = 0; ff < 2; ++ff)
              acc[ff][ip][nfl] = mfma16h(a[ff][ip], b[nfl], acc[ff][ip][nfl]);
        __builtin_amdgcn_s_setprio(0);
      };
      for (int t2 = 0; t2 < 24; ++t2) {
        loadB2(bb, wp + 2048);
        vstep(2 * t2, ba);
        if (t2 != 23) loadB2(ba, wp + 4096);
        vstep(2 * t2 + 1, bb);
        wp += 4096;
      }
    }

    // ---- kh-pair reduce in LDS, then plain store ----
    if (kh == 1) {
#pragma unroll
      for (int ff = 0; ff < 2; ++ff)
#pragma unroll
        for (int ip = 0; ip < 3; ++ip)
#pragma unroll
          for (int nfl = 0; nfl < 2; ++nfl)
            dump[nh][(ff * 3 + ip) * 2 + nfl][lane] = acc[ff][ip][nfl];
    }
    __syncthreads();
    if (kh == 0) {
#pragma unroll
      for (int ff = 0; ff < 2; ++ff)
#pragma unroll
        for (int ip = 0; ip < 3; ++ip)
#pragma unroll
          for (int nfl = 0; nfl < 2; ++nfl) {
            f4v v = acc[ff][ip][nfl] + dump[nh][(ff * 3 + ip) * 2 + nfl][lane];
            int n = (nh * 2 + nfl) * 16 + r;
#pragma unroll
            for (int reg = 0; reg < 4; ++reg) {
              int rowo = ip * B_ + b0 + ff * 16 + q * 4 + reg;
              acc_ve[(size_t)rowo * 64 + n] = v[reg];
            }
          }
    }
  }
}

// ---------------- epilogue: silu / sigmoid-gating, interleaved output ----------------
__global__ void epilogue(const float* __restrict__ sc, const float* __restrict__ ve,
                         float* __restrict__ out) {
  int t = blockIdx.x * blockDim.x + threadIdx.x;  // B*192 threads exactly
  int b = t / NW_, c = t % NW_;
  float v = sc[t];
  float sg = 1.0f / (1.0f + __expf(-v));
  if (c < 128) {
    out[(size_t)b * 320 + c] = v * sg;            // silu
  } else {
    int w = c - 128;
#pragma unroll
    for (int i = 0; i < 3; ++i) {
      float vv = ve[((size_t)i * B_ + b) * 64 + w];
      out[(size_t)b * 320 + 128 + w * 3 + i] = vv * sg;
    }
  }
}

// ---------------- launch ----------------
extern "C" void kernel_launch(void* const* d_in, const int* in_sizes, int n_in,
                              void* d_out, int out_size, void* d_ws, size_t ws_size,
                              hipStream_t stream) {
  const float* x    = (const float*)d_in[0];
  const float* w000 = (const float*)d_in[1];
  const float* w110 = (const float*)d_in[2];
  const float* w011 = (const float*)d_in[3];
  const float* w111 = (const float*)d_in[4];
  float* out = (float*)d_out;

  char* ws = (char*)d_ws;
  float* acc_sc = (float*)ws;                     // 8192*192*4  = 6,291,456 B
  float* acc_ve = (float*)(ws + 6291456);         // 3*8192*64*4 = 6,291,456 B
  short* wsc    = (short*)(ws + 12582912);        // 416*12*512*2 = 5,111,808 B
  short* wve    = (short*)(ws + 17694720);        // 352*4*512*2  = 1,441,792 B
  // total ws use: 19,136,512 B

  // No accumulator zeroing needed: gemm_fused plain-stores every element once.
  prep_all  <<<1600, 256, 0, stream>>>(w000, w110, w011, w111, wsc, wve);
  gemm_fused<<<512, 256, 0, stream>>>(x, wsc, wve, acc_sc, acc_ve);
  epilogue  <<<6144, 256, 0, stream>>>(acc_sc, acc_ve, out);
}

// Round 9
// 158.989 us; speedup vs baseline: 1.3236x; 1.1245x over previous
//
#include <hip/hip_runtime.h>
#include <cstdint>

// ---------------- problem constants ----------------
static constexpr int B_  = 8192;
static constexpr int NW_ = 192;                 // NS + NV

typedef __attribute__((ext_vector_type(8))) _Float16 h8v;
typedef __attribute__((ext_vector_type(2))) _Float16 h2v;
typedef __attribute__((ext_vector_type(4))) float f4v;
typedef __attribute__((ext_vector_type(2))) float f2v;
typedef __attribute__((ext_vector_type(4))) unsigned u4v;
typedef __attribute__((ext_vector_type(2))) unsigned u2v;

#define DI __device__ __forceinline__

DI h2v uh(unsigned u) { return __builtin_bit_cast(h2v, u); }
DI unsigned hu(h2v h) { return __builtin_bit_cast(unsigned, h); }
DI h2v hsplat(unsigned short bits) {
  _Float16 v = __builtin_bit_cast(_Float16, bits);
  h2v t; t.x = v; t.y = v; return t;
}
DI unsigned hpack(float lo, float hi) {
  h2v t; t.x = (_Float16)lo; t.y = (_Float16)hi;
  return __builtin_bit_cast(unsigned, t);
}
DI short f2h_bits(float f) { return __builtin_bit_cast(short, (_Float16)f); }

DI f4v mfma16h(h8v a, h8v b, f4v c) {
  return __builtin_amdgcn_mfma_f32_16x16x32_f16(a, b, c, 0, 0, 0);
}

// ---- block-symmetry tables (2 bits per block index) ----
static constexpr unsigned PK_BU0 = 606436u;   // {0,1,2,3,0,0,0,1,1,2}
static constexpr unsigned PK_BV0 = 1030628u;  // {0,1,2,3,1,2,3,2,3,3}
static constexpr unsigned PK_BU2 = 4u;        // {0,1,0}
static constexpr unsigned PK_BV2 = 20u;       // {0,1,1}
DI int tab2(unsigned pack, int blk) { return (int)((pack >> (2 * blk)) & 3u); }

// ---------------- prep (coalesced): 768 blocks x 256 threads ----------------
// blocks [0,416): sc fragments (one s each); [416,768): vec fragments.
// Loads are contiguous 96B/thread chunks (vs R8's scalar strided gather);
// LDS-transpose then contiguous 16B fragment stores.
__global__ void prep_all(const float* __restrict__ w000, const float* __restrict__ w110,
                         const float* __restrict__ w011, const float* __restrict__ w111,
                         short* __restrict__ wsc, short* __restrict__ wve) {
  __shared__ unsigned short T[32][200];
  const int t = threadIdx.x;
  const int bi = blockIdx.x;
  const float s000 = 1.0f / (128.0f * 1.41421356237f);   // (1/N0) * inv_sqrt2
  const float s110 = 1.0f / (64.0f * 2.44948974968f);    // (1/(N1*sqrt3)) * inv_sqrt2
  const float sv   = 1.0f / 128.0f;

  if (bi < 416) {
    const int s = bi;
    const float* W; int dim; float scale; int blk, ik, bu, bv;
    if (s < 320) {
      blk = s >> 5; ik = s & 31;
      bu = tab2(PK_BU0, blk); bv = tab2(PK_BV0, blk);
      W = w000; dim = 128; scale = s000;
    } else {
      int sp = s - 320; blk = sp >> 5; ik = sp & 31;
      bu = tab2(PK_BU2, blk); bv = tab2(PK_BV2, blk);
      W = w110; dim = 64; scale = s110;
    }
    const int u = bu * 32 + ik;
    const int v = t >> 3, l8 = t & 7;        // v-row 0..31; n-range l8*24..+24
    float a[24];
    const float* pA = W + ((size_t)(u * dim) + bv * 32 + v) * 192 + l8 * 24;
#pragma unroll
    for (int jj = 0; jj < 6; ++jj) {
      f4v x4 = *(const f4v*)(pA + jj * 4);
      a[jj * 4] = x4.x; a[jj * 4 + 1] = x4.y; a[jj * 4 + 2] = x4.z; a[jj * 4 + 3] = x4.w;
    }
    if (bu != bv) {
      const float* pB = W + ((size_t)((bv * 32 + v)) * dim + u) * 192 + l8 * 24;
#pragma unroll
      for (int jj = 0; jj < 6; ++jj) {
        f4v x4 = *(const f4v*)(pB + jj * 4);
        a[jj * 4] += x4.x; a[jj * 4 + 1] += x4.y; a[jj * 4 + 2] += x4.z; a[jj * 4 + 3] += x4.w;
      }
    }
    unsigned o[12];
#pragma unroll
    for (int i = 0; i < 12; ++i) o[i] = hpack(a[2 * i] * scale, a[2 * i + 1] * scale);
#pragma unroll
    for (int i = 0; i < 3; ++i)
      *(u4v*)(&T[v][l8 * 24 + i * 8]) = u4v{o[4 * i], o[4 * i + 1], o[4 * i + 2], o[4 * i + 3]};
    __syncthreads();
    short* dst = wsc + (size_t)s * 6144;
#pragma unroll
    for (int k = 0; k < 3; ++k) {
      const int unit = t * 3 + k;            // 768 units of (F,lane)
      const int F = unit >> 6, lane = unit & 63;
      const int n = F * 16 + (lane & 15);
      const int vr = (lane >> 4) * 8;
      short oo[8];
#pragma unroll
      for (int j = 0; j < 8; ++j) oo[j] = (short)T[vr + j][n];
      *(h8v*)(dst + F * 512 + lane * 8) = *(h8v*)oo;
    }
  } else {
    const int s = bi - 416;                  // 0..351
    if (s < 256) {
      const int k32 = t >> 3, l8 = t & 7;    // n-range l8*8..+8
      const float* p = w011 + ((size_t)(s * 32 + k32)) * 64 + l8 * 8;
      f4v x0_ = *(const f4v*)p, x1_ = *(const f4v*)(p + 4);
      u4v o{hpack(x0_.x * sv, x0_.y * sv), hpack(x0_.z * sv, x0_.w * sv),
            hpack(x1_.x * sv, x1_.y * sv), hpack(x1_.z * sv, x1_.w * sv)};
      *(u4v*)(&T[k32][l8 * 8]) = o;
    } else {
      const int sp = s - 256;
      const int blk = sp >> 5, ik = sp & 31;
      const int bu = tab2(PK_BU2, blk), bv = tab2(PK_BV2, blk);
      const int u = bu * 32 + ik;
      const int v = t >> 3, l8 = t & 7;
      float a[8];
      const float* pA = w111 + ((size_t)(u * 64) + bv * 32 + v) * 64 + l8 * 8;
      f4v x0_ = *(const f4v*)pA, x1_ = *(const f4v*)(pA + 4);
      a[0] = x0_.x; a[1] = x0_.y; a[2] = x0_.z; a[3] = x0_.w;
      a[4] = x1_.x; a[5] = x1_.y; a[6] = x1_.z; a[7] = x1_.w;
      if (bu != bv) {
        const float* pB = w111 + ((size_t)((bv * 32 + v)) * 64 + u) * 64 + l8 * 8;
        f4v y0 = *(const f4v*)pB, y1 = *(const f4v*)(pB + 4);
        a[0] -= y0.x; a[1] -= y0.y; a[2] -= y0.z; a[3] -= y0.w;
        a[4] -= y1.x; a[5] -= y1.y; a[6] -= y1.z; a[7] -= y1.w;
      }
      u4v o{hpack(a[0] * sv, a[1] * sv), hpack(a[2] * sv, a[3] * sv),
            hpack(a[4] * sv, a[5] * sv), hpack(a[6] * sv, a[7] * sv)};
      *(u4v*)(&T[v][l8 * 8]) = o;
    }
    __syncthreads();
    const int nf = t >> 6, lane = t & 63;    // 256 threads = 256 units
    const int n = nf * 16 + (lane & 15);
    const int vr = (lane >> 4) * 8;
    short oo[8];
#pragma unroll
    for (int j = 0; j < 8; ++j) oo[j] = (short)T[vr + j][n];
    *(h8v*)(wve + (size_t)s * 2048 + nf * 512 + lane * 8) = *(h8v*)oo;
  }
}

// ---------------- LDS staging: 32 rows of x, f16, 512 threads ----------------
#define X0H_STRIDE 136
#define X1_STRIDE  200

DI void stage_x32w(const float* __restrict__ x, int b0,
                   unsigned short* X0H, unsigned short* X1) {
  const int t = threadIdx.x;            // 512 threads
  const int row = t >> 4, l16 = t & 15; // 32 rows x 16 lanes
  const float* src = x + (size_t)(b0 + row) * 320;
  f4v v0 = *(const f4v*)(src + l16 * 8);
  f4v v1 = *(const f4v*)(src + l16 * 8 + 4);
  u4v o{hpack(v0.x, v0.y), hpack(v0.z, v0.w), hpack(v1.x, v1.y), hpack(v1.z, v1.w)};
  *(u4v*)(&X0H[row * X0H_STRIDE + l16 * 8]) = o;
  float buf[12];
  f4v a0 = *(const f4v*)(src + 128 + l16 * 12);
  f4v a1 = *(const f4v*)(src + 128 + l16 * 12 + 4);
  f4v a2 = *(const f4v*)(src + 128 + l16 * 12 + 8);
  buf[0] = a0.x; buf[1] = a0.y; buf[2] = a0.z; buf[3] = a0.w;
  buf[4] = a1.x; buf[5] = a1.y; buf[6] = a1.z; buf[7] = a1.w;
  buf[8] = a2.x; buf[9] = a2.y; buf[10] = a2.z; buf[11] = a2.w;
#pragma unroll
  for (int i = 0; i < 3; ++i) {
    u2v w2{hpack(buf[i], buf[3 + i]), hpack(buf[6 + i], buf[9 + i])};
    *(u2v*)(&X1[row * X1_STRIDE + i * 64 + l16 * 4]) = w2;
  }
}

DI void loadB6(h8v* dst, const short* __restrict__ p) {
#pragma unroll
  for (int nf = 0; nf < 6; ++nf) dst[nf] = *(const h8v*)(p + nf * 512);
}
DI void loadB2(h8v* dst, const short* __restrict__ p) {
  dst[0] = *(const h8v*)p;
  dst[1] = *(const h8v*)(p + 512);
}

// ---------------- mega-kernel: sc + vec + fused epilogue, one block per tile ----------------
// R9: grid 256 x 512 threads (8 waves: w0-3 sc {nh,kh}, w4-7 vec {nh,kh}).
// - Perfect sc/vec balance (R8 had a ~40us sc-only tail at half occupancy).
// - x staged ONCE per tile (R8 staged it twice, in separate sc/vec blocks).
// - Depth-3 B prefetch (4 rotating buffers): load-to-use distance ~360cy; the
//   2-waves/SIMD config has a 256-reg budget so the R2/R5 VGPR cliff can't bite.
// - Epilogue fused: kh-reduce in LDS, sc waves emit silu + sigmoid-gates (LDS),
//   vec waves emit gated interleaved output. No acc round-trip, no 3rd kernel.
__global__ __launch_bounds__(512, 2)
void gemm_fused(const float* __restrict__ x, const short* __restrict__ wsc,
                const short* __restrict__ wve, float* __restrict__ out) {
  __shared__ unsigned short X0H[32 * X0H_STRIDE];   // 8704 B
  __shared__ unsigned short X1[32 * X1_STRIDE];     // 12800 B
  __shared__ f4v dump[4][12][64];                   // 49152 B  [slot][acc][lane]
  __shared__ float G[32][64];                       // 8192 B   sigmoid gates
  const int b0 = blockIdx.x * 32;

  stage_x32w(x, b0, X0H, X1);
  __syncthreads();

  const int t0 = threadIdx.x;
  const int w = t0 >> 6, lane = t0 & 63;   // w in 0..7
  const bool isvec = w >= 4;
  const int nh = w & 1, kh = (w >> 1) & 1;
  const int q = lane >> 4, r = lane & 15, q8 = q * 8;

  f4v acc[12];
#pragma unroll
  for (int i = 0; i < 12; ++i) acc[i] = f4v{0.f, 0.f, 0.f, 0.f};

  if (!isvec) {
    // ================= scalar path =================
    const unsigned short* x0f[2];
    const unsigned short* x1f[2];
#pragma unroll
    for (int f = 0; f < 2; ++f) {
      x0f[f] = &X0H[(f * 16 + r) * X0H_STRIDE];
      x1f[f] = &X1[(f * 16 + r) * X1_STRIDE];
    }

    // ---- region 1: x0 pair blocks, 160 steps (K-half kh), depth-3 prefetch ----
    {
      const int s0 = kh * 160;
      const short* wp = wsc + ((size_t)s0 * 12 + nh * 6) * 512 + lane * 8;
      u4v pv[2]; pv[0] = u4v{0, 0, 0, 0}; pv[1] = u4v{0, 0, 0, 0};
      int bu32 = 0;
      h8v b[4][6];
      loadB6(b[0], wp); loadB6(b[1], wp + 6144); loadB6(b[2], wp + 12288);
      for (int t4 = 0; t4 < 40; ++t4) {
#pragma unroll
        for (int uu = 0; uu < 4; ++uu) {
          const int t = t4 * 4 + uu;
          if (t < 157) loadB6(b[(uu + 3) & 3], wp + (size_t)(t + 3) * 6144);
          const int s = s0 + t;
          const int ik = s & 31;
          if (t == 0 || ik == 0) {      // new 32x32 block (wave-uniform)
            const int blk = s >> 5;
            const int bv32 = tab2(PK_BV0, blk) * 32;
            bu32 = tab2(PK_BU0, blk) * 32;
            pv[0] = *(const u4v*)(x0f[0] + bv32 + q8);
            pv[1] = *(const u4v*)(x0f[1] + bv32 + q8);
          }
          h8v a[2];
#pragma unroll
          for (int f = 0; f < 2; ++f) {
            h2v xu = hsplat(x0f[f][bu32 + ik]);
            u4v pa;
#pragma unroll
            for (int m = 0; m < 4; ++m) pa[m] = hu(uh(pv[f][m]) * xu);
            a[f] = __builtin_bit_cast(h8v, pa);
          }
          __builtin_amdgcn_s_setprio(1);
#pragma unroll
          for (int nf = 0; nf < 6; ++nf)
#pragma unroll
            for (int f = 0; f < 2; ++f)
              acc[f * 6 + nf] = mfma16h(a[f], b[uu & 3][nf], acc[f * 6 + nf]);
          __builtin_amdgcn_s_setprio(0);
        }
      }
    }

    // ---- region 2: x1-dots pair blocks, 48 steps (K-half kh) ----
    {
      const int sp0 = kh * 48;
      const short* wp = wsc + ((size_t)(320 + sp0) * 12 + nh * 6) * 512 + lane * 8;
      h8v b[4][6];
      loadB6(b[0], wp); loadB6(b[1], wp + 6144); loadB6(b[2], wp + 12288);
      for (int t4 = 0; t4 < 12; ++t4) {
#pragma unroll
        for (int uu = 0; uu < 4; ++uu) {
          const int t = t4 * 4 + uu;
          if (t < 45) loadB6(b[(uu + 3) & 3], wp + (size_t)(t + 3) * 6144);
          const int sp = sp0 + t;
          const int blk = sp >> 5, ik = sp & 31;
          const int bu32 = tab2(PK_BU2, blk) * 32;
          const int bv32 = tab2(PK_BV2, blk) * 32;
          h8v a[2];
#pragma unroll
          for (int f = 0; f < 2; ++f) {
            h2v us0 = hsplat(x1f[f][bu32 + ik]);
            h2v us1 = hsplat(x1f[f][64 + bu32 + ik]);
            h2v us2 = hsplat(x1f[f][128 + bu32 + ik]);
            u4v p0 = *(const u4v*)(x1f[f] + bv32 + q8);
            u4v p1 = *(const u4v*)(x1f[f] + 64 + bv32 + q8);
            u4v p2 = *(const u4v*)(x1f[f] + 128 + bv32 + q8);
            u4v pa;
#pragma unroll
            for (int m = 0; m < 4; ++m) {
              h2v sm = uh(p0[m]) * us0;
              sm = sm + uh(p1[m]) * us1;
              sm = sm + uh(p2[m]) * us2;
              pa[m] = hu(sm);
            }
            a[f] = __builtin_bit_cast(h8v, pa);
          }
          __builtin_amdgcn_s_setprio(1);
#pragma unroll
          for (int nf = 0; nf < 6; ++nf)
#pragma unroll
            for (int f = 0; f < 2; ++f)
              acc[f * 6 + nf] = mfma16h(a[f], b[uu & 3][nf], acc[f * 6 + nf]);
          __builtin_amdgcn_s_setprio(0);
        }
      }
    }
  } else {
    // ================= vector path =================
    const unsigned short* x0r[2];
    const unsigned short* x1r[2];
#pragma unroll
    for (int ff = 0; ff < 2; ++ff) {
      x0r[ff] = &X0H[(ff * 16 + r) * X0H_STRIDE];
      x1r[ff] = &X1[(ff * 16 + r) * X1_STRIDE];
    }

    // ---- region 1: v011, 128 steps (u in [kh*64,+64), j in {0,1}), depth-3 ----
    {
      const int u0 = kh * 64;
      const short* wp = wve + (size_t)(u0 * 2) * 2048 + nh * 1024 + lane * 8;
      h8v b[4][2];
      loadB2(b[0], wp); loadB2(b[1], wp + 2048); loadB2(b[2], wp + 4096);
      for (int t4 = 0; t4 < 32; ++t4) {
#pragma unroll
        for (int uu = 0; uu < 4; ++uu) {
          const int t = t4 * 4 + uu;
          if (t < 125) loadB2(b[(uu + 3) & 3], wp + (size_t)(t + 3) * 2048);
          const int g = t >> 1, j = t & 1;
          const int vb = j * 32 + q8;
          h8v a[2][3];
#pragma unroll
          for (int ff = 0; ff < 2; ++ff) {
            h2v xu2 = hsplat(x0r[ff][u0 + g]);
#pragma unroll
            for (int i = 0; i < 3; ++i) {
              u4v p = *(const u4v*)(x1r[ff] + i * 64 + vb);
              u4v pa;
#pragma unroll
              for (int m = 0; m < 4; ++m) pa[m] = hu(uh(p[m]) * xu2);
              a[ff][i] = __builtin_bit_cast(h8v, pa);
            }
          }
          __builtin_amdgcn_s_setprio(1);
#pragma unroll
          for (int ip = 0; ip < 3; ++ip)
#pragma unroll
            for (int nfl = 0; nfl < 2; ++nfl)
#pragma unroll
              for (int ff = 0; ff < 2; ++ff)
                acc[(ff * 3 + ip) * 2 + nfl] =
                    mfma16h(a[ff][ip], b[uu & 3][nfl], acc[(ff * 3 + ip) * 2 + nfl]);
          __builtin_amdgcn_s_setprio(0);
        }
      }
    }

    // ---- region 2: v111 antisym, 48 steps (sp in [kh*48,+48)) ----
    {
      const int sp0 = kh * 48;
      const short* wp = wve + (size_t)(256 + sp0) * 2048 + nh * 1024 + lane * 8;
      h8v b[4][2];
      loadB2(b[0], wp); loadB2(b[1], wp + 2048); loadB2(b[2], wp + 4096);
      for (int t4 = 0; t4 < 12; ++t4) {
#pragma unroll
        for (int uu = 0; uu < 4; ++uu) {
          const int t = t4 * 4 + uu;
          if (t < 45) loadB2(b[(uu + 3) & 3], wp + (size_t)(t + 3) * 2048);
          const int sp = sp0 + t;
          const int blk = sp >> 5, ik = sp & 31;
          const int bu32 = tab2(PK_BU2, blk) * 32;
          const int bv32 = tab2(PK_BV2, blk) * 32;
          h8v a[2][3];
#pragma unroll
          for (int ff = 0; ff < 2; ++ff) {
            h2v us[3];
            u4v p[3];
#pragma unroll
            for (int i = 0; i < 3; ++i) {
              us[i] = hsplat(x1r[ff][i * 64 + bu32 + ik]);
              p[i] = *(const u4v*)(x1r[ff] + i * 64 + bv32 + q8);
            }
#pragma unroll
            for (int ip = 0; ip < 3; ++ip) {
              const int i1 = (ip + 1) % 3, i2 = (ip + 2) % 3;
              u4v pa;
#pragma unroll
              for (int m = 0; m < 4; ++m)
                pa[m] = hu(uh(p[i2][m]) * us[i1] - uh(p[i1][m]) * us[i2]);
              a[ff][ip] = __builtin_bit_cast(h8v, pa);
            }
          }
          __builtin_amdgcn_s_setprio(1);
#pragma unroll
          for (int ip = 0; ip < 3; ++ip)
#pragma unroll
            for (int nfl = 0; nfl < 2; ++nfl)
#pragma unroll
              for (int ff = 0; ff < 2; ++ff)
                acc[(ff * 3 + ip) * 2 + nfl] =
                    mfma16h(a[ff][ip], b[uu & 3][nfl], acc[(ff * 3 + ip) * 2 + nfl]);
          __builtin_amdgcn_s_setprio(0);
        }
      }
    }
  }

  // ---- kh-pair reduce + fused epilogue ----
  const int slot = (isvec ? 2 : 0) + nh;
  if (kh == 1) {
#pragma unroll
    for (int i = 0; i < 12; ++i) dump[slot][i][lane] = acc[i];
  }
  __syncthreads();

  if (kh == 0 && !isvec) {
    // scalar outputs: silu for n<128, sigmoid gates -> LDS for n>=128
#pragma unroll
    for (int f = 0; f < 2; ++f)
#pragma unroll
      for (int nf = 0; nf < 6; ++nf) {
        f4v v = acc[f * 6 + nf] + dump[slot][f * 6 + nf][lane];
        const int n = (nh * 6 + nf) * 16 + r;
#pragma unroll
        for (int reg = 0; reg < 4; ++reg) {
          const int row = f * 16 + q * 4 + reg;
          const float val = v[reg];
          const float sg = 1.0f / (1.0f + __expf(-val));
          if (n < 128) out[(size_t)(b0 + row) * 320 + n] = val * sg;
          else         G[row][n - 128] = sg;
        }
      }
  }
  __syncthreads();                       // gates ready

  if (kh == 0 && isvec) {
#pragma unroll
    for (int ff = 0; ff < 2; ++ff)
#pragma unroll
      for (int ip = 0; ip < 3; ++ip)
#pragma unroll
        for (int nfl = 0; nfl < 2; ++nfl) {
          const int ai = (ff * 3 + ip) * 2 + nfl;
          f4v v = acc[ai] + dump[slot][ai][lane];
          const int n = (nh * 2 + nfl) * 16 + r;
#pragma unroll
          for (int reg = 0; reg < 4; ++reg) {
            const int row = ff * 16 + q * 4 + reg;
            out[(size_t)(b0 + row) * 320 + 128 + n * 3 + ip] = v[reg] * G[row][n];
          }
        }
  }
}

// ---------------- launch ----------------
extern "C" void kernel_launch(void* const* d_in, const int* in_sizes, int n_in,
                              void* d_out, int out_size, void* d_ws, size_t ws_size,
                              hipStream_t stream) {
  const float* x    = (const float*)d_in[0];
  const float* w000 = (const float*)d_in[1];
  const float* w110 = (const float*)d_in[2];
  const float* w011 = (const float*)d_in[3];
  const float* w111 = (const float*)d_in[4];
  float* out = (float*)d_out;

  char* ws = (char*)d_ws;
  short* wsc = (short*)ws;                        // 416*6144*2 = 5,111,808 B
  short* wve = (short*)(ws + 5111808);            // 352*2048*2 = 1,441,792 B
  // total ws use: 6,553,600 B (no accumulators — epilogue fused into gemm)

  prep_all  <<<768, 256, 0, stream>>>(w000, w110, w011, w111, wsc, wve);
  gemm_fused<<<256, 512, 0, stream>>>(x, wsc, wve, out);
}

// Round 10
// 158.635 us; speedup vs baseline: 1.3265x; 1.0022x over previous
//
#include <hip/hip_runtime.h>
#include <cstdint>

// ---------------- problem constants ----------------
static constexpr int B_  = 8192;
static constexpr int NW_ = 192;                 // NS + NV

typedef __attribute__((ext_vector_type(8))) _Float16 h8v;
typedef __attribute__((ext_vector_type(2))) _Float16 h2v;
typedef __attribute__((ext_vector_type(4))) float f4v;
typedef __attribute__((ext_vector_type(2))) float f2v;
typedef __attribute__((ext_vector_type(4))) unsigned u4v;
typedef __attribute__((ext_vector_type(2))) unsigned u2v;

#define DI __device__ __forceinline__

DI h2v uh(unsigned u) { return __builtin_bit_cast(h2v, u); }
DI unsigned hu(h2v h) { return __builtin_bit_cast(unsigned, h); }
DI h2v hsplat(unsigned short bits) {
  _Float16 v = __builtin_bit_cast(_Float16, bits);
  h2v t; t.x = v; t.y = v; return t;
}
// splat half (lo/hi, compile-time after unroll) of a register strip word
DI h2v dupw(unsigned w, int hi) {
  unsigned bits = hi ? (w >> 16) : (w & 0xffffu);
  return uh(bits | (bits << 16));
}
DI unsigned hpack(float lo, float hi) {
  h2v t; t.x = (_Float16)lo; t.y = (_Float16)hi;
  return __builtin_bit_cast(unsigned, t);
}
DI short f2h_bits(float f) { return __builtin_bit_cast(short, (_Float16)f); }

DI f4v mfma16h(h8v a, h8v b, f4v c) {
  return __builtin_amdgcn_mfma_f32_16x16x32_f16(a, b, c, 0, 0, 0);
}

// ---- block-symmetry tables (2 bits per block index) ----
static constexpr unsigned PK_BU0 = 606436u;   // {0,1,2,3,0,0,0,1,1,2}
static constexpr unsigned PK_BV0 = 1030628u;  // {0,1,2,3,1,2,3,2,3,3}
static constexpr unsigned PK_BU2 = 4u;        // {0,1,0}
static constexpr unsigned PK_BV2 = 20u;       // {0,1,1}
DI int tab2(unsigned pack, int blk) { return (int)((pack >> (2 * blk)) & 3u); }

// ---------------- prep (coalesced): 768 blocks x 256 threads ----------------
__global__ void prep_all(const float* __restrict__ w000, const float* __restrict__ w110,
                         const float* __restrict__ w011, const float* __restrict__ w111,
                         short* __restrict__ wsc, short* __restrict__ wve) {
  __shared__ unsigned short T[32][200];
  const int t = threadIdx.x;
  const int bi = blockIdx.x;
  const float s000 = 1.0f / (128.0f * 1.41421356237f);   // (1/N0) * inv_sqrt2
  const float s110 = 1.0f / (64.0f * 2.44948974968f);    // (1/(N1*sqrt3)) * inv_sqrt2
  const float sv   = 1.0f / 128.0f;

  if (bi < 416) {
    const int s = bi;
    const float* W; int dim; float scale; int blk, ik, bu, bv;
    if (s < 320) {
      blk = s >> 5; ik = s & 31;
      bu = tab2(PK_BU0, blk); bv = tab2(PK_BV0, blk);
      W = w000; dim = 128; scale = s000;
    } else {
      int sp = s - 320; blk = sp >> 5; ik = sp & 31;
      bu = tab2(PK_BU2, blk); bv = tab2(PK_BV2, blk);
      W = w110; dim = 64; scale = s110;
    }
    const int u = bu * 32 + ik;
    const int v = t >> 3, l8 = t & 7;
    float a[24];
    const float* pA = W + ((size_t)(u * dim) + bv * 32 + v) * 192 + l8 * 24;
#pragma unroll
    for (int jj = 0; jj < 6; ++jj) {
      f4v x4 = *(const f4v*)(pA + jj * 4);
      a[jj * 4] = x4.x; a[jj * 4 + 1] = x4.y; a[jj * 4 + 2] = x4.z; a[jj * 4 + 3] = x4.w;
    }
    if (bu != bv) {
      const float* pB = W + ((size_t)((bv * 32 + v)) * dim + u) * 192 + l8 * 24;
#pragma unroll
      for (int jj = 0; jj < 6; ++jj) {
        f4v x4 = *(const f4v*)(pB + jj * 4);
        a[jj * 4] += x4.x; a[jj * 4 + 1] += x4.y; a[jj * 4 + 2] += x4.z; a[jj * 4 + 3] += x4.w;
      }
    }
    unsigned o[12];
#pragma unroll
    for (int i = 0; i < 12; ++i) o[i] = hpack(a[2 * i] * scale, a[2 * i + 1] * scale);
#pragma unroll
    for (int i = 0; i < 3; ++i)
      *(u4v*)(&T[v][l8 * 24 + i * 8]) = u4v{o[4 * i], o[4 * i + 1], o[4 * i + 2], o[4 * i + 3]};
    __syncthreads();
    short* dst = wsc + (size_t)s * 6144;
#pragma unroll
    for (int k = 0; k < 3; ++k) {
      const int unit = t * 3 + k;
      const int F = unit >> 6, lane = unit & 63;
      const int n = F * 16 + (lane & 15);
      const int vr = (lane >> 4) * 8;
      short oo[8];
#pragma unroll
      for (int j = 0; j < 8; ++j) oo[j] = (short)T[vr + j][n];
      *(h8v*)(dst + F * 512 + lane * 8) = *(h8v*)oo;
    }
  } else {
    const int s = bi - 416;
    if (s < 256) {
      const int k32 = t >> 3, l8 = t & 7;
      const float* p = w011 + ((size_t)(s * 32 + k32)) * 64 + l8 * 8;
      f4v x0_ = *(const f4v*)p, x1_ = *(const f4v*)(p + 4);
      u4v o{hpack(x0_.x * sv, x0_.y * sv), hpack(x0_.z * sv, x0_.w * sv),
            hpack(x1_.x * sv, x1_.y * sv), hpack(x1_.z * sv, x1_.w * sv)};
      *(u4v*)(&T[k32][l8 * 8]) = o;
    } else {
      const int sp = s - 256;
      const int blk = sp >> 5, ik = sp & 31;
      const int bu = tab2(PK_BU2, blk), bv = tab2(PK_BV2, blk);
      const int u = bu * 32 + ik;
      const int v = t >> 3, l8 = t & 7;
      float a[8];
      const float* pA = w111 + ((size_t)(u * 64) + bv * 32 + v) * 64 + l8 * 8;
      f4v x0_ = *(const f4v*)pA, x1_ = *(const f4v*)(pA + 4);
      a[0] = x0_.x; a[1] = x0_.y; a[2] = x0_.z; a[3] = x0_.w;
      a[4] = x1_.x; a[5] = x1_.y; a[6] = x1_.z; a[7] = x1_.w;
      if (bu != bv) {
        const float* pB = w111 + ((size_t)((bv * 32 + v)) * 64 + u) * 64 + l8 * 8;
        f4v y0 = *(const f4v*)pB, y1 = *(const f4v*)(pB + 4);
        a[0] -= y0.x; a[1] -= y0.y; a[2] -= y0.z; a[3] -= y0.w;
        a[4] -= y1.x; a[5] -= y1.y; a[6] -= y1.z; a[7] -= y1.w;
      }
      u4v o{hpack(a[0] * sv, a[1] * sv), hpack(a[2] * sv, a[3] * sv),
            hpack(a[4] * sv, a[5] * sv), hpack(a[6] * sv, a[7] * sv)};
      *(u4v*)(&T[v][l8 * 8]) = o;
    }
    __syncthreads();
    const int nf = t >> 6, lane = t & 63;
    const int n = nf * 16 + (lane & 15);
    const int vr = (lane >> 4) * 8;
    short oo[8];
#pragma unroll
    for (int j = 0; j < 8; ++j) oo[j] = (short)T[vr + j][n];
    *(h8v*)(wve + (size_t)s * 2048 + nf * 512 + lane * 8) = *(h8v*)oo;
  }
}

// ---------------- LDS staging: 32 rows of x, f16, 512 threads ----------------
#define X0H_STRIDE 136
#define X1_STRIDE  200

DI void stage_x32w(const float* __restrict__ x, int b0,
                   unsigned short* X0H, unsigned short* X1) {
  const int t = threadIdx.x;            // 512 threads
  const int row = t >> 4, l16 = t & 15; // 32 rows x 16 lanes
  const float* src = x + (size_t)(b0 + row) * 320;
  f4v v0 = *(const f4v*)(src + l16 * 8);
  f4v v1 = *(const f4v*)(src + l16 * 8 + 4);
  u4v o{hpack(v0.x, v0.y), hpack(v0.z, v0.w), hpack(v1.x, v1.y), hpack(v1.z, v1.w)};
  *(u4v*)(&X0H[row * X0H_STRIDE + l16 * 8]) = o;
  float buf[12];
  f4v a0 = *(const f4v*)(src + 128 + l16 * 12);
  f4v a1 = *(const f4v*)(src + 128 + l16 * 12 + 4);
  f4v a2 = *(const f4v*)(src + 128 + l16 * 12 + 8);
  buf[0] = a0.x; buf[1] = a0.y; buf[2] = a0.z; buf[3] = a0.w;
  buf[4] = a1.x; buf[5] = a1.y; buf[6] = a1.z; buf[7] = a1.w;
  buf[8] = a2.x; buf[9] = a2.y; buf[10] = a2.z; buf[11] = a2.w;
#pragma unroll
  for (int i = 0; i < 3; ++i) {
    u2v w2{hpack(buf[i], buf[3 + i]), hpack(buf[6 + i], buf[9 + i])};
    *(u2v*)(&X1[row * X1_STRIDE + i * 64 + l16 * 4]) = w2;
  }
}

DI void loadB6(h8v* dst, const short* __restrict__ p) {
#pragma unroll
  for (int nf = 0; nf < 6; ++nf) dst[nf] = *(const h8v*)(p + nf * 512);
}
DI void loadB2(h8v* dst, const short* __restrict__ p) {
  dst[0] = *(const h8v*)p;
  dst[1] = *(const h8v*)(p + 512);
}

// ---------------- mega-kernel: sc + vec + fused epilogue, A-hoisted ----------------
// R10 = R9 + register-hoisted A-strips (the R2 optimization, now free at
// 2 waves/SIMD where the register budget is 256): sc r1 in 8-step groups
// (1 ds_read_b128 per 8 steps), r2 in 4-step groups, vec r1 v-strips hoisted
// per 128 steps + xu strips per 16. Hot loops are pure register A-pack +
// depth-3 B prefetch + MFMA. Keep arch VGPR <= 208 (acc=48; cliff at 256).
__global__ __launch_bounds__(512, 2)
void gemm_fused(const float* __restrict__ x, const short* __restrict__ wsc,
                const short* __restrict__ wve, float* __restrict__ out) {
  __shared__ unsigned short X0H[32 * X0H_STRIDE];   // 8704 B
  __shared__ unsigned short X1[32 * X1_STRIDE];     // 12800 B
  __shared__ f4v dump[4][12][64];                   // 49152 B
  __shared__ float G[32][64];                       // 8192 B
  const int b0 = blockIdx.x * 32;

  stage_x32w(x, b0, X0H, X1);
  __syncthreads();

  const int t0 = threadIdx.x;
  const int w = t0 >> 6, lane = t0 & 63;   // w in 0..7
  const bool isvec = w >= 4;
  const int nh = w & 1, kh = (w >> 1) & 1;
  const int q = lane >> 4, r = lane & 15, q8 = q * 8;

  f4v acc[12];
#pragma unroll
  for (int i = 0; i < 12; ++i) acc[i] = f4v{0.f, 0.f, 0.f, 0.f};

  if (!isvec) {
    // ================= scalar path =================
    const unsigned short* x0f[2];
    const unsigned short* x1f[2];
#pragma unroll
    for (int f = 0; f < 2; ++f) {
      x0f[f] = &X0H[(f * 16 + r) * X0H_STRIDE];
      x1f[f] = &X1[(f * 16 + r) * X1_STRIDE];
    }

    // ---- region 1: x0 pair blocks, 160 steps = 20 groups x 8 ----
    {
      const int s0 = kh * 160;
      const short* wp = wsc + ((size_t)s0 * 12 + nh * 6) * 512 + lane * 8;
      u4v pv[2]; pv[0] = u4v{0, 0, 0, 0}; pv[1] = u4v{0, 0, 0, 0};
      int bu32 = 0;
      h8v b[4][6];
      loadB6(b[0], wp); loadB6(b[1], wp + 6144); loadB6(b[2], wp + 12288);
      for (int g5 = 0; g5 < 20; ++g5) {
        const int ss = g5 * 8;
        const int s = s0 + ss;
        const int ik0 = s & 31;
        if (g5 == 0 || ik0 == 0) {      // new 32x32 block (edges 8-aligned)
          const int blk = s >> 5;
          const int bv32 = tab2(PK_BV0, blk) * 32;
          bu32 = tab2(PK_BU0, blk) * 32;
          pv[0] = *(const u4v*)(x0f[0] + bv32 + q8);
          pv[1] = *(const u4v*)(x0f[1] + bv32 + q8);
        }
        const u4v ao0 = *(const u4v*)(x0f[0] + bu32 + ik0);  // 8-half u-strip
        const u4v ao1 = *(const u4v*)(x0f[1] + bu32 + ik0);
#pragma unroll
        for (int tt = 0; tt < 8; ++tt) {
          const int t = ss + tt;
          if (t < 157) loadB6(b[(t + 3) & 3], wp + (size_t)(t + 3) * 6144);
          h2v xu0 = dupw(ao0[tt >> 1], tt & 1);
          h2v xu1 = dupw(ao1[tt >> 1], tt & 1);
          u4v pa0, pa1;
#pragma unroll
          for (int m = 0; m < 4; ++m) {
            pa0[m] = hu(uh(pv[0][m]) * xu0);
            pa1[m] = hu(uh(pv[1][m]) * xu1);
          }
          h8v a0 = __builtin_bit_cast(h8v, pa0);
          h8v a1 = __builtin_bit_cast(h8v, pa1);
          __builtin_amdgcn_s_setprio(1);
#pragma unroll
          for (int nf = 0; nf < 6; ++nf) {
            acc[nf]     = mfma16h(a0, b[t & 3][nf], acc[nf]);
            acc[6 + nf] = mfma16h(a1, b[t & 3][nf], acc[6 + nf]);
          }
          __builtin_amdgcn_s_setprio(0);
        }
      }
    }

    // ---- region 2: x1-dots pair blocks, 48 steps = 12 groups x 4 ----
    {
      const int sp0 = kh * 48;
      const short* wp = wsc + ((size_t)(320 + sp0) * 12 + nh * 6) * 512 + lane * 8;
      h8v b[4][6];
      loadB6(b[0], wp); loadB6(b[1], wp + 6144); loadB6(b[2], wp + 12288);
      u4v pA[2][3];
      int bu32 = 0;
      for (int g3 = 0; g3 < 12; ++g3) {
        const int spg = sp0 + g3 * 4;
        const int ik0 = spg & 31;
        if (g3 == 0 || ik0 == 0) {      // block edges are 4-aligned
          const int blk = spg >> 5;
          const int bv32 = tab2(PK_BV2, blk) * 32;
          bu32 = tab2(PK_BU2, blk) * 32;
#pragma unroll
          for (int f = 0; f < 2; ++f)
#pragma unroll
            for (int i = 0; i < 3; ++i)
              pA[f][i] = *(const u4v*)(x1f[f] + i * 64 + bv32 + q8);
        }
        u2v qq[2][3];                   // 4-half u-quads
#pragma unroll
        for (int f = 0; f < 2; ++f)
#pragma unroll
          for (int i = 0; i < 3; ++i)
            qq[f][i] = *(const u2v*)(x1f[f] + i * 64 + bu32 + ik0);
#pragma unroll
        for (int tt = 0; tt < 4; ++tt) {
          const int t = g3 * 4 + tt;
          if (t < 45) loadB6(b[(t + 3) & 3], wp + (size_t)(t + 3) * 6144);
          h8v a[2];
#pragma unroll
          for (int f = 0; f < 2; ++f) {
            h2v us0 = dupw(qq[f][0][tt >> 1], tt & 1);
            h2v us1 = dupw(qq[f][1][tt >> 1], tt & 1);
            h2v us2 = dupw(qq[f][2][tt >> 1], tt & 1);
            u4v pa;
#pragma unroll
            for (int m = 0; m < 4; ++m) {
              h2v sm = uh(pA[f][0][m]) * us0;
              sm = sm + uh(pA[f][1][m]) * us1;
              sm = sm + uh(pA[f][2][m]) * us2;
              pa[m] = hu(sm);
            }
            a[f] = __builtin_bit_cast(h8v, pa);
          }
          __builtin_amdgcn_s_setprio(1);
#pragma unroll
          for (int nf = 0; nf < 6; ++nf) {
            acc[nf]     = mfma16h(a[0], b[t & 3][nf], acc[nf]);
            acc[6 + nf] = mfma16h(a[1], b[t & 3][nf], acc[6 + nf]);
          }
          __builtin_amdgcn_s_setprio(0);
        }
      }
    }
  } else {
    // ================= vector path =================
    const unsigned short* x0r[2];
    const unsigned short* x1r[2];
#pragma unroll
    for (int ff = 0; ff < 2; ++ff) {
      x0r[ff] = &X0H[(ff * 16 + r) * X0H_STRIDE];
      x1r[ff] = &X1[(ff * 16 + r) * X1_STRIDE];
    }

    // ---- region 1: v011, 128 steps = 8 groups x 16; v-strips fully hoisted ----
    {
      const int u0 = kh * 64;
      const short* wp = wve + (size_t)(u0 * 2) * 2048 + nh * 1024 + lane * 8;
      h8v b[4][2];
      loadB2(b[0], wp); loadB2(b[1], wp + 2048); loadB2(b[2], wp + 4096);
      u4v pj[2][2][3];                  // [j][ff][i] — chunk-invariant
#pragma unroll
      for (int j = 0; j < 2; ++j)
#pragma unroll
        for (int ff = 0; ff < 2; ++ff)
#pragma unroll
          for (int i = 0; i < 3; ++i)
            pj[j][ff][i] = *(const u4v*)(x1r[ff] + i * 64 + j * 32 + q8);
      for (int g8 = 0; g8 < 8; ++g8) {
        const u4v st0 = *(const u4v*)(x0r[0] + u0 + g8 * 8);  // 8 xu halves
        const u4v st1 = *(const u4v*)(x0r[1] + u0 + g8 * 8);
#pragma unroll
        for (int tt = 0; tt < 16; ++tt) {
          const int t = g8 * 16 + tt;
          if (t < 125) loadB2(b[(t + 3) & 3], wp + (size_t)(t + 3) * 2048);
          const int gg = tt >> 1, j = tt & 1;
          h2v xu0 = dupw(st0[gg >> 1], gg & 1);
          h2v xu1 = dupw(st1[gg >> 1], gg & 1);
          h8v a[2][3];
#pragma unroll
          for (int ff = 0; ff < 2; ++ff) {
            h2v xu2 = ff ? xu1 : xu0;
#pragma unroll
            for (int i = 0; i < 3; ++i) {
              u4v pa;
#pragma unroll
              for (int m = 0; m < 4; ++m) pa[m] = hu(uh(pj[j][ff][i][m]) * xu2);
              a[ff][i] = __builtin_bit_cast(h8v, pa);
            }
          }
          __builtin_amdgcn_s_setprio(1);
#pragma unroll
          for (int ip = 0; ip < 3; ++ip)
#pragma unroll
            for (int nfl = 0; nfl < 2; ++nfl)
#pragma unroll
              for (int ff = 0; ff < 2; ++ff)
                acc[(ff * 3 + ip) * 2 + nfl] =
                    mfma16h(a[ff][ip], b[t & 3][nfl], acc[(ff * 3 + ip) * 2 + nfl]);
          __builtin_amdgcn_s_setprio(0);
        }
      }
    }

    // ---- region 2: v111 antisym, 48 steps = 12 groups x 4 ----
    {
      const int sp0 = kh * 48;
      const short* wp = wve + (size_t)(256 + sp0) * 2048 + nh * 1024 + lane * 8;
      h8v b[4][2];
      loadB2(b[0], wp); loadB2(b[1], wp + 2048); loadB2(b[2], wp + 4096);
      u4v pp[2][3];
      int bu32 = 0;
      for (int g3 = 0; g3 < 12; ++g3) {
        const int spg = sp0 + g3 * 4;
        const int ik0 = spg & 31;
        if (g3 == 0 || ik0 == 0) {
          const int blk = spg >> 5;
          const int bv32 = tab2(PK_BV2, blk) * 32;
          bu32 = tab2(PK_BU2, blk) * 32;
#pragma unroll
          for (int ff = 0; ff < 2; ++ff)
#pragma unroll
            for (int i = 0; i < 3; ++i)
              pp[ff][i] = *(const u4v*)(x1r[ff] + i * 64 + bv32 + q8);
        }
        u2v qq[2][3];
#pragma unroll
        for (int ff = 0; ff < 2; ++ff)
#pragma unroll
          for (int i = 0; i < 3; ++i)
            qq[ff][i] = *(const u2v*)(x1r[ff] + i * 64 + bu32 + ik0);
#pragma unroll
        for (int tt = 0; tt < 4; ++tt) {
          const int t = g3 * 4 + tt;
          if (t < 45) loadB2(b[(t + 3) & 3], wp + (size_t)(t + 3) * 2048);
          h8v a[2][3];
#pragma unroll
          for (int ff = 0; ff < 2; ++ff) {
            h2v us[3];
#pragma unroll
            for (int i = 0; i < 3; ++i) us[i] = dupw(qq[ff][i][tt >> 1], tt & 1);
#pragma unroll
            for (int ip = 0; ip < 3; ++ip) {
              const int i1 = (ip + 1) % 3, i2 = (ip + 2) % 3;
              u4v pa;
#pragma unroll
              for (int m = 0; m < 4; ++m)
                pa[m] = hu(uh(pp[ff][i2][m]) * us[i1] - uh(pp[ff][i1][m]) * us[i2]);
              a[ff][ip] = __builtin_bit_cast(h8v, pa);
            }
          }
          __builtin_amdgcn_s_setprio(1);
#pragma unroll
          for (int ip = 0; ip < 3; ++ip)
#pragma unroll
            for (int nfl = 0; nfl < 2; ++nfl)
#pragma unroll
              for (int ff = 0; ff < 2; ++ff)
                acc[(ff * 3 + ip) * 2 + nfl] =
                    mfma16h(a[ff][ip], b[t & 3][nfl], acc[(ff * 3 + ip) * 2 + nfl]);
          __builtin_amdgcn_s_setprio(0);
        }
      }
    }
  }

  // ---- kh-pair reduce + fused epilogue ----
  const int slot = (isvec ? 2 : 0) + nh;
  if (kh == 1) {
#pragma unroll
    for (int i = 0; i < 12; ++i) dump[slot][i][lane] = acc[i];
  }
  __syncthreads();

  if (kh == 0 && !isvec) {
#pragma unroll
    for (int f = 0; f < 2; ++f)
#pragma unroll
      for (int nf = 0; nf < 6; ++nf) {
        f4v v = acc[f * 6 + nf] + dump[slot][f * 6 + nf][lane];
        const int n = (nh * 6 + nf) * 16 + r;
#pragma unroll
        for (int reg = 0; reg < 4; ++reg) {
          const int row = f * 16 + q * 4 + reg;
          const float val = v[reg];
          const float sg = 1.0f / (1.0f + __expf(-val));
          if (n < 128) out[(size_t)(b0 + row) * 320 + n] = val * sg;
          else         G[row][n - 128] = sg;
        }
      }
  }
  __syncthreads();                       // gates ready

  if (kh == 0 && isvec) {
#pragma unroll
    for (int ff = 0; ff < 2; ++ff)
#pragma unroll
      for (int ip = 0; ip < 3; ++ip)
#pragma unroll
        for (int nfl = 0; nfl < 2; ++nfl) {
          const int ai = (ff * 3 + ip) * 2 + nfl;
          f4v v = acc[ai] + dump[slot][ai][lane];
          const int n = (nh * 2 + nfl) * 16 + r;
#pragma unroll
          for (int reg = 0; reg < 4; ++reg) {
            const int row = ff * 16 + q * 4 + reg;
            out[(size_t)(b0 + row) * 320 + 128 + n * 3 + ip] = v[reg] * G[row][n];
          }
        }
  }
}

// ---------------- launch ----------------
extern "C" void kernel_launch(void* const* d_in, const int* in_sizes, int n_in,
                              void* d_out, int out_size, void* d_ws, size_t ws_size,
                              hipStream_t stream) {
  const float* x    = (const float*)d_in[0];
  const float* w000 = (const float*)d_in[1];
  const float* w110 = (const float*)d_in[2];
  const float* w011 = (const float*)d_in[3];
  const float* w111 = (const float*)d_in[4];
  float* out = (float*)d_out;

  char* ws = (char*)d_ws;
  short* wsc = (short*)ws;                        // 416*6144*2 = 5,111,808 B
  short* wve = (short*)(ws + 5111808);            // 352*2048*2 = 1,441,792 B

  prep_all  <<<768, 256, 0, stream>>>(w000, w110, w011, w111, wsc, wve);
  gemm_fused<<<256, 512, 0, stream>>>(x, wsc, wve, out);
}